// Round 4
// baseline (263.874 us; speedup 1.0000x reference)
//
#include <hip/hip_runtime.h>
#include <stdint.h>

// DETR post-process: per batch n of 256, top-300 of sigmoid(logits[n]) (80000
// elems), output [label, score, scaled box] per selected query.
//
// Ordering: jax top_k = score desc, tie -> lowest index. sigmoid is strictly
// monotonic, so we rank on 64-bit key (ord(logit)<<32 | ~index): descending
// key order == (score desc, index asc) exactly.
//
// R8 = R7 with the hipMemsetAsync replaced by a zero-kernel (graph-capture
// safety: only kernel launches on the stream).
//   K0 (zero):  1 block, zeros the 256 per-batch candidate counters.
//   K1 (scan):  8 blocks/batch x 256 threads -> 32 waves/CU, pure streaming
//     float4; compacts logits >= 2.4f into per-batch global candidate array
//     (cap 2048) via per-batch global atomic counter (~650/batch, rare).
//     (R6's monolithic 1024-thread scan was 4 waves/SIMD = latency-bound at
//     ~3.3 TB/s; fills on the same chip/graph hit 6.6 TB/s.)
//   K2 (rank):  one 1024-thread block per batch. Fast path: load candidates
//     from global, monotone 512-bin histogram rank (single-wave shfl suffix
//     scan), scatter, exact within-bin tie count, emit. If cnt outside
//     [TOPK, CAP]: full radix-select fallback re-reading logits (correct for
//     arbitrary data, never taken for the bench input).
//   If ws_size < required ~4.2 MB: monolithic R6 kernel fallback.
//
// Hard-learned rules: NO per-thread arrays with runtime indexing (R2/R3:
// scratch spill, WRITE_SIZE 49/161 MB). All load indices compile-time affine.
// R6 lesson: rank-phase barriers were NOT the bottleneck; scan occupancy was.

#define TOPK 300
#define NCLS 80
#define NQ 1000
#define QK (NQ * NCLS)   // 80000
#define NB 2048          // fallback radix bins
#define CAP 2048
#define THREADS 1024
#define LAST_VALID 544   // j=19: 4*t + 4096*19 < 80000  <=>  t < 544
#define T0F 2.4f         // fixed fast-path threshold (z-score)
#define RNB 512          // rank bins
#define RSH 14           // rank-bin shift: bin = (ord - base) >> RSH

// K1 geometry: 8 blocks per batch, 256 threads, 10000 floats (2500 float4)
// per block; j=0..8 full, j=9 partial (t < 196).
#define SBLK 8
#define STHREADS 256
#define SCHUNK 10000
#define SLAST 196

typedef unsigned long long u64;

__device__ __forceinline__ uint32_t ordf(float f) {
  uint32_t u = __float_as_uint(f);
  return (u & 0x80000000u) ? ~u : (u | 0x80000000u);  // monotonic float->uint
}
__device__ __forceinline__ float unordf(uint32_t o) {
  uint32_t u = (o & 0x80000000u) ? (o & 0x7fffffffu) : ~o;
  return __uint_as_float(u);
}
__device__ __forceinline__ u64 mkkey(uint32_t ord, uint32_t idx) {
  return ((u64)ord << 32) | (u64)(~idx);
}

// ---------------- K0: zero the per-batch counters (graph-safe) -------------
__global__ __launch_bounds__(STHREADS) void zero_kernel(
    uint32_t* __restrict__ cnts, int nbatch) {
  const int i = blockIdx.x * STHREADS + threadIdx.x;
  if (i < nbatch) cnts[i] = 0;
}

// ---------------- K1: full-occupancy streaming scan + global compact -------
__global__ __launch_bounds__(STHREADS) void scan_kernel(
    const float* __restrict__ logits, u64* __restrict__ cand,
    uint32_t* __restrict__ cnts) {
  const int n = blockIdx.x >> 3;        // batch
  const int rb = blockIdx.x & 7;        // chunk within batch
  const int t = threadIdx.x;
  const int coff = rb * SCHUNK;
  const float* lg = logits + (size_t)n * QK + coff;
  u64* cnd = cand + (size_t)n * CAP;
  uint32_t* cp = cnts + n;

#pragma unroll
  for (int j = 0; j < 10; ++j) {
    if (j == 9 && t >= SLAST) break;
    const int i = 4 * (t + STHREADS * j);
    const float4 v = *(const float4*)(lg + i);
    const int gi = coff + i;
    if (v.x >= T0F) {
      const uint32_t p = atomicAdd(cp, 1u);
      if (p < CAP) cnd[p] = mkkey(ordf(v.x), (uint32_t)(gi + 0));
    }
    if (v.y >= T0F) {
      const uint32_t p = atomicAdd(cp, 1u);
      if (p < CAP) cnd[p] = mkkey(ordf(v.y), (uint32_t)(gi + 1));
    }
    if (v.z >= T0F) {
      const uint32_t p = atomicAdd(cp, 1u);
      if (p < CAP) cnd[p] = mkkey(ordf(v.z), (uint32_t)(gi + 2));
    }
    if (v.w >= T0F) {
      const uint32_t p = atomicAdd(cp, 1u);
      if (p < CAP) cnd[p] = mkkey(ordf(v.w), (uint32_t)(gi + 3));
    }
  }
}

// ---------------- shared rank+emit helper ----------------------------------
__device__ __forceinline__ void rank_emit(
    const u64 key, const uint32_t bin, const uint32_t* rcur,
    const uint32_t* rh, const u64* buf2, const float* boxes, float* out,
    const int n, const float s0, const float s1) {
  const uint32_t end = rcur[bin];          // start[bin] + count[bin]
  const uint32_t beg = end - rh[bin];
  uint32_t rank = beg;                     // #keys in strictly-higher bins
  for (uint32_t q = beg; q < end; ++q) rank += (uint32_t)(buf2[q] > key);
  if (rank < TOPK) {
    const uint32_t u = (uint32_t)(key >> 32);
    const uint32_t idx = ~(uint32_t)(key & 0xffffffffu);
    const float lgv = unordf(u);
    const float score = 1.0f / (1.0f + expf(-lgv));
    const uint32_t q = idx / NCLS;
    const uint32_t lab = idx - q * NCLS;
    const float4 b4 = *(const float4*)(boxes + ((size_t)n * NQ + q) * 4);
    float* op = out + ((size_t)n * TOPK + rank) * 6;  // 8-byte aligned
    float2* op2 = (float2*)op;
    op2[0] = make_float2((float)lab, score);
    op2[1] = make_float2((b4.x - 0.5f * b4.z) * s1, (b4.y - 0.5f * b4.w) * s0);
    op2[2] = make_float2(b4.z * s1, b4.w * s0);
  }
}

// ---------------- K2: rank + emit (fallback: radix re-reading logits) ------
__global__ __launch_bounds__(THREADS) void rank_kernel(
    const float* __restrict__ logits, const float* __restrict__ boxes,
    const int* __restrict__ osz, float* __restrict__ out,
    const u64* __restrict__ cand, const uint32_t* __restrict__ cnts) {
  __shared__ u64 buf[CAP];       // 16 KB: fallback compaction buffer
  __shared__ u64 smem64[4096];   // 32 KB: fallback hist4 | {buf2, rh, rcur}
  __shared__ uint32_t histf[NB]; // 8 KB: fallback prefix only
  __shared__ uint32_t sh_sel[3];
  __shared__ uint32_t sh_cnt;

  uint32_t* const hist4 = (uint32_t*)smem64;        // 8192 u32 (fallback)
  u64* const buf2 = smem64;                         // 2048 u64 (rank scatter)
  uint32_t* const rh = (uint32_t*)(smem64 + 2048);  // 512 u32 (bin counts)
  uint32_t* const rcur = (uint32_t*)(smem64 + 2304);// 512 u32 (start/cursor)

  const int n = blockIdx.x;
  const int t = threadIdx.x;
  const float* lg = logits + (size_t)n * QK;

  if (t < RNB) rh[t] = 0;

  uint32_t cnt = cnts[n];
  const bool fast_ok = (cnt >= TOPK && cnt <= CAP);  // block-uniform
  uint32_t baseord = ordf(T0F);

  u64 k0 = 0, k1 = 0;
  if (fast_ok) {
    const u64* cnd = cand + (size_t)n * CAP;
    if ((uint32_t)t < cnt) k0 = cnd[t];
    if ((uint32_t)(t + THREADS) < cnt) k1 = cnd[t + THREADS];
    __syncthreads();  // rh init visible
  } else {
    // ---- fallback: full radix select on ord(logit), then recompact to LDS.
    // Correct for arbitrary inputs; never taken for the bench distribution.
    __syncthreads();
    uint32_t T = 0, S_above = 0, Krem = TOPK;
    int prev_shift = 32;
    const uint32_t sub = (uint32_t)(t & 3);
    const int shifts[3] = {21, 10, 0};
    const int nbns[3] = {2048, 2048, 1024};

    for (int lvl = 0; lvl < 3; ++lvl) {
      const int sh = shifts[lvl];
      const uint32_t nb = (uint32_t)nbns[lvl];

      for (int b = t; b < NB * 4; b += THREADS) hist4[b] = 0;
      __syncthreads();
      for (int j = 0; j < 20; ++j) {
        if (j == 19 && t >= LAST_VALID) break;
        const int i = 4 * t + 4096 * j;
        const float4 v = *(const float4*)(lg + i);
        const float vs[4] = {v.x, v.y, v.z, v.w};
        for (int c = 0; c < 4; ++c) {
          const uint32_t u = ordf(vs[c]);
          if (lvl == 0 || (u >> prev_shift) == (T >> prev_shift))
            atomicAdd(&hist4[(((u >> sh) & (nb - 1)) << 2) | sub], 1u);
        }
      }
      __syncthreads();

      for (uint32_t b = t; b < nb; b += (uint32_t)THREADS) {
        const uint32_t i4 = b << 2;
        histf[b] = hist4[i4] + hist4[i4 + 1] + hist4[i4 + 2] + hist4[i4 + 3];
      }
      __syncthreads();

      for (uint32_t off = 1; off < nb; off <<= 1) {
        uint32_t a0 = histf[t] + ((t + off < nb) ? histf[t + off] : 0u);
        uint32_t a1 = 0;
        if (nb > (uint32_t)THREADS) {
          const uint32_t i1 = (uint32_t)t + THREADS;
          a1 = histf[i1] + ((i1 + off < nb) ? histf[i1 + off] : 0u);
        }
        __syncthreads();
        histf[t] = a0;
        if (nb > (uint32_t)THREADS) histf[(uint32_t)t + THREADS] = a1;
        __syncthreads();
      }

      for (uint32_t b = t; b < nb; b += (uint32_t)THREADS) {
        const uint32_t s = histf[b];
        const uint32_t sn = (b + 1 < nb) ? histf[b + 1] : 0u;
        if (s >= Krem && sn < Krem) {
          sh_sel[0] = b;
          sh_sel[1] = sn;
          sh_sel[2] = s;
        }
      }
      __syncthreads();
      const uint32_t bsel = sh_sel[0], above = sh_sel[1], candL = sh_sel[2];
      __syncthreads();

      T |= bsel << sh;
      if (S_above + candL <= CAP || lvl == 2) break;
      S_above += above;
      Krem -= above;
      prev_shift = sh;
    }

    // recompact with the radix-derived ordered threshold; re-zero rank bins
    if (t == 0) sh_cnt = 0;
    __syncthreads();
    if (t < RNB) rh[t] = 0;
    for (int j = 0; j < 20; ++j) {
      if (j == 19 && t >= LAST_VALID) break;
      const int i = 4 * t + 4096 * j;
      const float4 v = *(const float4*)(lg + i);
      const float vs[4] = {v.x, v.y, v.z, v.w};
      for (int c = 0; c < 4; ++c) {
        const uint32_t u = ordf(vs[c]);
        if (u >= T) {
          const uint32_t p = atomicAdd(&sh_cnt, 1u);
          if (p < CAP) buf[p] = mkkey(u, (uint32_t)(i + c));
        }
      }
    }
    __syncthreads();
    cnt = sh_cnt < CAP ? sh_cnt : CAP;
    baseord = T;  // all compacted keys have ord >= T
    if ((uint32_t)t < cnt) k0 = buf[t];
    if ((uint32_t)(t + THREADS) < cnt) k1 = buf[t + THREADS];
  }

  // ---- rank via monotone 512-bin histogram on (ord - baseord) >> RSH.
  // bin(a) > bin(b)  =>  a > b  (strict), so
  // rank(key) = (#keys in higher bins) + (#same-bin keys > key)  -- exact.
  uint32_t b0 = 0, b1 = 0;
  if ((uint32_t)t < cnt) {
    b0 = ((uint32_t)(k0 >> 32) - baseord) >> RSH;
    if (b0 > RNB - 1u) b0 = RNB - 1u;
    atomicAdd(&rh[b0], 1u);
  }
  if ((uint32_t)(t + THREADS) < cnt) {
    b1 = ((uint32_t)(k1 >> 32) - baseord) >> RSH;
    if (b1 > RNB - 1u) b1 = RNB - 1u;
    atomicAdd(&rh[b1], 1u);
  }
  __syncthreads();

  // ---- single-wave suffix scan: rcur[b] = sum_{b' > b} rh[b']  (start[b])
  if (t < 64) {
    const uint4 a = *(const uint4*)&rh[8 * t];
    const uint4 b = *(const uint4*)&rh[8 * t + 4];
    const uint32_t c0 = a.x, c1 = a.y, c2 = a.z, c3 = a.w;
    const uint32_t c4 = b.x, c5 = b.y, c6 = b.z, c7 = b.w;
    const uint32_t mysum = c0 + c1 + c2 + c3 + c4 + c5 + c6 + c7;
    uint32_t s = mysum;  // inclusive suffix over lanes
    for (int d = 1; d < 64; d <<= 1) {
      const uint32_t o = __shfl_down(s, d);
      if (t + d < 64) s += o;
    }
    uint32_t acc = s - mysum;  // sum over lanes > t
    rcur[8 * t + 7] = acc; acc += c7;
    rcur[8 * t + 6] = acc; acc += c6;
    rcur[8 * t + 5] = acc; acc += c5;
    rcur[8 * t + 4] = acc; acc += c4;
    rcur[8 * t + 3] = acc; acc += c3;
    rcur[8 * t + 2] = acc; acc += c2;
    rcur[8 * t + 1] = acc; acc += c1;
    rcur[8 * t + 0] = acc;
  }
  __syncthreads();

  // ---- scatter candidates into bin-ordered slots of buf2
  if ((uint32_t)t < cnt) {
    const uint32_t s = atomicAdd(&rcur[b0], 1u);
    buf2[s] = k0;
  }
  if ((uint32_t)(t + THREADS) < cnt) {
    const uint32_t s = atomicAdd(&rcur[b1], 1u);
    buf2[s] = k1;
  }
  __syncthreads();
  // now rcur[b] = start[b] + rh[b] = segment end for bin b

  const float s0 = (float)osz[0];
  const float s1 = (float)osz[1];

  if ((uint32_t)t < cnt)
    rank_emit(k0, b0, rcur, rh, buf2, boxes, out, n, s0, s1);
  if ((uint32_t)(t + THREADS) < cnt)
    rank_emit(k1, b1, rcur, rh, buf2, boxes, out, n, s0, s1);
}

// ---------------- monolithic R6 kernel: used only if ws too small ----------
__global__ __launch_bounds__(THREADS) void detr_post_mono(
    const float* __restrict__ logits, const float* __restrict__ boxes,
    const int* __restrict__ osz, float* __restrict__ out) {
  __shared__ u64 buf[CAP];
  __shared__ u64 smem64[4096];
  __shared__ uint32_t histf[NB];
  __shared__ uint32_t sh_sel[3];
  __shared__ uint32_t sh_cnt;

  uint32_t* const hist4 = (uint32_t*)smem64;
  u64* const buf2 = smem64;
  uint32_t* const rh = (uint32_t*)(smem64 + 2048);
  uint32_t* const rcur = (uint32_t*)(smem64 + 2304);

  const int n = blockIdx.x;
  const int t = threadIdx.x;
  const float* lg = logits + (size_t)n * QK;

  if (t == 0) sh_cnt = 0;
  if (t < RNB) rh[t] = 0;
  __syncthreads();

#pragma unroll 5
  for (int j = 0; j < 19; ++j) {
    const int i = 4 * t + 4096 * j;
    const float4 v = *(const float4*)(lg + i);
    if (v.x >= T0F) {
      const uint32_t p = atomicAdd(&sh_cnt, 1u);
      if (p < CAP) buf[p] = mkkey(ordf(v.x), (uint32_t)(i + 0));
    }
    if (v.y >= T0F) {
      const uint32_t p = atomicAdd(&sh_cnt, 1u);
      if (p < CAP) buf[p] = mkkey(ordf(v.y), (uint32_t)(i + 1));
    }
    if (v.z >= T0F) {
      const uint32_t p = atomicAdd(&sh_cnt, 1u);
      if (p < CAP) buf[p] = mkkey(ordf(v.z), (uint32_t)(i + 2));
    }
    if (v.w >= T0F) {
      const uint32_t p = atomicAdd(&sh_cnt, 1u);
      if (p < CAP) buf[p] = mkkey(ordf(v.w), (uint32_t)(i + 3));
    }
  }
  if (t < LAST_VALID) {
    const int i = 4 * t + 4096 * 19;
    const float4 v = *(const float4*)(lg + i);
    if (v.x >= T0F) {
      const uint32_t p = atomicAdd(&sh_cnt, 1u);
      if (p < CAP) buf[p] = mkkey(ordf(v.x), (uint32_t)(i + 0));
    }
    if (v.y >= T0F) {
      const uint32_t p = atomicAdd(&sh_cnt, 1u);
      if (p < CAP) buf[p] = mkkey(ordf(v.y), (uint32_t)(i + 1));
    }
    if (v.z >= T0F) {
      const uint32_t p = atomicAdd(&sh_cnt, 1u);
      if (p < CAP) buf[p] = mkkey(ordf(v.z), (uint32_t)(i + 2));
    }
    if (v.w >= T0F) {
      const uint32_t p = atomicAdd(&sh_cnt, 1u);
      if (p < CAP) buf[p] = mkkey(ordf(v.w), (uint32_t)(i + 3));
    }
  }
  __syncthreads();

  uint32_t cnt = sh_cnt;
  const bool fast_ok = (cnt >= TOPK && cnt <= CAP);
  uint32_t baseord = ordf(T0F);

  if (!fast_ok) {
    uint32_t T = 0, S_above = 0, Krem = TOPK;
    int prev_shift = 32;
    const uint32_t sub = (uint32_t)(t & 3);
    const int shifts[3] = {21, 10, 0};
    const int nbns[3] = {2048, 2048, 1024};

    for (int lvl = 0; lvl < 3; ++lvl) {
      const int sh = shifts[lvl];
      const uint32_t nb = (uint32_t)nbns[lvl];

      for (int b = t; b < NB * 4; b += THREADS) hist4[b] = 0;
      __syncthreads();
      for (int j = 0; j < 20; ++j) {
        if (j == 19 && t >= LAST_VALID) break;
        const int i = 4 * t + 4096 * j;
        const float4 v = *(const float4*)(lg + i);
        const float vs[4] = {v.x, v.y, v.z, v.w};
        for (int c = 0; c < 4; ++c) {
          const uint32_t u = ordf(vs[c]);
          if (lvl == 0 || (u >> prev_shift) == (T >> prev_shift))
            atomicAdd(&hist4[(((u >> sh) & (nb - 1)) << 2) | sub], 1u);
        }
      }
      __syncthreads();

      for (uint32_t b = t; b < nb; b += (uint32_t)THREADS) {
        const uint32_t i4 = b << 2;
        histf[b] = hist4[i4] + hist4[i4 + 1] + hist4[i4 + 2] + hist4[i4 + 3];
      }
      __syncthreads();

      for (uint32_t off = 1; off < nb; off <<= 1) {
        uint32_t a0 = histf[t] + ((t + off < nb) ? histf[t + off] : 0u);
        uint32_t a1 = 0;
        if (nb > (uint32_t)THREADS) {
          const uint32_t i1 = (uint32_t)t + THREADS;
          a1 = histf[i1] + ((i1 + off < nb) ? histf[i1 + off] : 0u);
        }
        __syncthreads();
        histf[t] = a0;
        if (nb > (uint32_t)THREADS) histf[(uint32_t)t + THREADS] = a1;
        __syncthreads();
      }

      for (uint32_t b = t; b < nb; b += (uint32_t)THREADS) {
        const uint32_t s = histf[b];
        const uint32_t sn = (b + 1 < nb) ? histf[b + 1] : 0u;
        if (s >= Krem && sn < Krem) {
          sh_sel[0] = b;
          sh_sel[1] = sn;
          sh_sel[2] = s;
        }
      }
      __syncthreads();
      const uint32_t bsel = sh_sel[0], above = sh_sel[1], candL = sh_sel[2];
      __syncthreads();

      T |= bsel << sh;
      if (S_above + candL <= CAP || lvl == 2) break;
      S_above += above;
      Krem -= above;
      prev_shift = sh;
    }

    if (t == 0) sh_cnt = 0;
    __syncthreads();
    if (t < RNB) rh[t] = 0;
    for (int j = 0; j < 20; ++j) {
      if (j == 19 && t >= LAST_VALID) break;
      const int i = 4 * t + 4096 * j;
      const float4 v = *(const float4*)(lg + i);
      const float vs[4] = {v.x, v.y, v.z, v.w};
      for (int c = 0; c < 4; ++c) {
        const uint32_t u = ordf(vs[c]);
        if (u >= T) {
          const uint32_t p = atomicAdd(&sh_cnt, 1u);
          if (p < CAP) buf[p] = mkkey(u, (uint32_t)(i + c));
        }
      }
    }
    __syncthreads();
    cnt = sh_cnt < CAP ? sh_cnt : CAP;
    baseord = T;
  }

  const u64 k0 = ((uint32_t)t < cnt) ? buf[t] : 0ULL;
  const u64 k1 = ((uint32_t)(t + THREADS) < cnt) ? buf[t + THREADS] : 0ULL;
  uint32_t b0 = 0, b1 = 0;
  if ((uint32_t)t < cnt) {
    b0 = ((uint32_t)(k0 >> 32) - baseord) >> RSH;
    if (b0 > RNB - 1u) b0 = RNB - 1u;
    atomicAdd(&rh[b0], 1u);
  }
  if ((uint32_t)(t + THREADS) < cnt) {
    b1 = ((uint32_t)(k1 >> 32) - baseord) >> RSH;
    if (b1 > RNB - 1u) b1 = RNB - 1u;
    atomicAdd(&rh[b1], 1u);
  }
  __syncthreads();

  if (t < 64) {
    const uint4 a = *(const uint4*)&rh[8 * t];
    const uint4 b = *(const uint4*)&rh[8 * t + 4];
    const uint32_t c0 = a.x, c1 = a.y, c2 = a.z, c3 = a.w;
    const uint32_t c4 = b.x, c5 = b.y, c6 = b.z, c7 = b.w;
    const uint32_t mysum = c0 + c1 + c2 + c3 + c4 + c5 + c6 + c7;
    uint32_t s = mysum;
    for (int d = 1; d < 64; d <<= 1) {
      const uint32_t o = __shfl_down(s, d);
      if (t + d < 64) s += o;
    }
    uint32_t acc = s - mysum;
    rcur[8 * t + 7] = acc; acc += c7;
    rcur[8 * t + 6] = acc; acc += c6;
    rcur[8 * t + 5] = acc; acc += c5;
    rcur[8 * t + 4] = acc; acc += c4;
    rcur[8 * t + 3] = acc; acc += c3;
    rcur[8 * t + 2] = acc; acc += c2;
    rcur[8 * t + 1] = acc; acc += c1;
    rcur[8 * t + 0] = acc;
  }
  __syncthreads();

  if ((uint32_t)t < cnt) {
    const uint32_t s = atomicAdd(&rcur[b0], 1u);
    buf2[s] = k0;
  }
  if ((uint32_t)(t + THREADS) < cnt) {
    const uint32_t s = atomicAdd(&rcur[b1], 1u);
    buf2[s] = k1;
  }
  __syncthreads();

  const float s0 = (float)osz[0];
  const float s1 = (float)osz[1];

  if ((uint32_t)t < cnt)
    rank_emit(k0, b0, rcur, rh, buf2, boxes, out, n, s0, s1);
  if ((uint32_t)(t + THREADS) < cnt)
    rank_emit(k1, b1, rcur, rh, buf2, boxes, out, n, s0, s1);
}

extern "C" void kernel_launch(void* const* d_in, const int* in_sizes, int n_in,
                              void* d_out, int out_size, void* d_ws, size_t ws_size,
                              hipStream_t stream) {
  const float* logits = (const float*)d_in[0];
  const float* boxes = (const float*)d_in[1];
  const int* osz = (const int*)d_in[2];
  float* out = (float*)d_out;
  const int nbatch = in_sizes[0] / QK;  // 256

  // ws layout: [cnts: nbatch u32, padded to 1024 B][cand: nbatch*CAP u64]
  const size_t cnt_bytes = 1024;
  const size_t need = cnt_bytes + (size_t)nbatch * CAP * sizeof(u64);
  if (d_ws != nullptr && ws_size >= need && (size_t)nbatch * 4 <= cnt_bytes) {
    uint32_t* cnts = (uint32_t*)d_ws;
    u64* cand = (u64*)((char*)d_ws + cnt_bytes);
    const int zblocks = (nbatch + STHREADS - 1) / STHREADS;
    zero_kernel<<<zblocks, STHREADS, 0, stream>>>(cnts, nbatch);
    scan_kernel<<<nbatch * SBLK, STHREADS, 0, stream>>>(logits, cand, cnts);
    rank_kernel<<<nbatch, THREADS, 0, stream>>>(logits, boxes, osz, out, cand,
                                                cnts);
  } else {
    detr_post_mono<<<nbatch, THREADS, 0, stream>>>(logits, boxes, osz, out);
  }
}

// Round 5
// 125.963 us; speedup vs baseline: 2.0949x; 2.0949x over previous
//
#include <hip/hip_runtime.h>
#include <stdint.h>

// DETR post-process: per batch n of 256, top-300 of sigmoid(logits[n]) (80000
// elems), output [label, score, scaled box] per selected query.
//
// Ordering: jax top_k = score desc, tie -> lowest index. sigmoid is strictly
// monotonic, so we rank on 64-bit key (ord(logit)<<32 | ~index): descending
// key order == (score desc, index asc) exactly.
//
// R9 structure: three kernels through d_ws.
//   K0 (zero):  zeros the 256 per-batch candidate counters (graph-safe).
//   K1 (scan):  8 blocks/batch x 256 threads (32 waves/CU). TWO-LEVEL
//     compaction: candidates >= 2.4f go into a per-block LDS buffer via LDS
//     atomics (rare branch, ~82/block); then ONE global atomicAdd per block
//     reserves a contiguous slice of the per-batch global candidate array;
//     coalesced LDS->global copy. R8 LESSON: per-candidate global atomicAdd
//     with dependent store = ~650 serialized cross-XCD round-trips per batch
//     -> 161 us at 300 GB/s, VALUBusy 2%. Atomic PLACEMENT, not grid shape,
//     was the bottleneck.
//   K2 (rank):  one 1024-thread block per batch. Fast path: load candidates
//     from global, monotone 512-bin histogram rank (single-wave shfl suffix
//     scan), scatter, exact within-bin tie count, emit. If cnt outside
//     [TOPK, CAP]: full radix-select fallback re-reading logits (correct for
//     arbitrary data, never taken for the bench input). Exact-count
//     invariant: K1 adds the TRUE local count even if its LDS buffer would
//     overflow, so overflow always lands in the fallback.
//   If ws_size < required ~4.2 MB: monolithic R6 kernel fallback.
//
// Hard-learned rules: NO per-thread arrays with runtime indexing (R2/R3:
// scratch spill). All load indices compile-time affine. No per-candidate
// global atomics (R8).

#define TOPK 300
#define NCLS 80
#define NQ 1000
#define QK (NQ * NCLS)   // 80000
#define NB 2048          // fallback radix bins
#define CAP 2048
#define THREADS 1024
#define LAST_VALID 544   // j=19: 4*t + 4096*19 < 80000  <=>  t < 544
#define T0F 2.4f         // fixed fast-path threshold (z-score)
#define RNB 512          // rank bins
#define RSH 14           // rank-bin shift: bin = (ord - base) >> RSH

// K1 geometry: 8 blocks per batch, 256 threads, 10000 floats (2500 float4)
// per block; j=0..8 full, j=9 partial (t < 196).
#define SBLK 8
#define STHREADS 256
#define SCHUNK 10000
#define SLAST 196
#define LCAP 2048        // per-block LDS candidate buffer (16 KB)

typedef unsigned long long u64;

__device__ __forceinline__ uint32_t ordf(float f) {
  uint32_t u = __float_as_uint(f);
  return (u & 0x80000000u) ? ~u : (u | 0x80000000u);  // monotonic float->uint
}
__device__ __forceinline__ float unordf(uint32_t o) {
  uint32_t u = (o & 0x80000000u) ? (o & 0x7fffffffu) : ~o;
  return __uint_as_float(u);
}
__device__ __forceinline__ u64 mkkey(uint32_t ord, uint32_t idx) {
  return ((u64)ord << 32) | (u64)(~idx);
}

// ---------------- K0: zero the per-batch counters (graph-safe) -------------
__global__ __launch_bounds__(STHREADS) void zero_kernel(
    uint32_t* __restrict__ cnts, int nbatch) {
  const int i = blockIdx.x * STHREADS + threadIdx.x;
  if (i < nbatch) cnts[i] = 0;
}

// ---------------- K1: streaming scan, two-level compaction -----------------
__global__ __launch_bounds__(STHREADS) void scan_kernel(
    const float* __restrict__ logits, u64* __restrict__ cand,
    uint32_t* __restrict__ cnts) {
  __shared__ u64 lbuf[LCAP];
  __shared__ uint32_t lcnt;
  __shared__ uint32_t sh_base;

  const int n = blockIdx.x >> 3;        // batch
  const int rb = blockIdx.x & 7;        // chunk within batch
  const int t = threadIdx.x;
  const int coff = rb * SCHUNK;
  const float* lg = logits + (size_t)n * QK + coff;

  if (t == 0) lcnt = 0;
  __syncthreads();

#pragma unroll
  for (int j = 0; j < 10; ++j) {
    if (j == 9 && t >= SLAST) break;
    const int i = 4 * (t + STHREADS * j);
    const float4 v = *(const float4*)(lg + i);
    const int gi = coff + i;
    if (v.x >= T0F) {
      const uint32_t p = atomicAdd(&lcnt, 1u);
      if (p < LCAP) lbuf[p] = mkkey(ordf(v.x), (uint32_t)(gi + 0));
    }
    if (v.y >= T0F) {
      const uint32_t p = atomicAdd(&lcnt, 1u);
      if (p < LCAP) lbuf[p] = mkkey(ordf(v.y), (uint32_t)(gi + 1));
    }
    if (v.z >= T0F) {
      const uint32_t p = atomicAdd(&lcnt, 1u);
      if (p < LCAP) lbuf[p] = mkkey(ordf(v.z), (uint32_t)(gi + 2));
    }
    if (v.w >= T0F) {
      const uint32_t p = atomicAdd(&lcnt, 1u);
      if (p < LCAP) lbuf[p] = mkkey(ordf(v.w), (uint32_t)(gi + 3));
    }
  }
  __syncthreads();

  const uint32_t lc = lcnt;  // exact local count (may exceed LCAP)
  if (t == 0) sh_base = atomicAdd(cnts + n, lc);  // ONE global atomic/block
  __syncthreads();
  const uint32_t base = sh_base;

  u64* cnd = cand + (size_t)n * CAP;
  const uint32_t lim = lc < LCAP ? lc : LCAP;
  for (uint32_t p = t; p < lim; p += STHREADS) {
    const uint32_t g = base + p;
    if (g < CAP) cnd[g] = lbuf[p];  // OOB only when total > CAP -> fallback
  }
}

// ---------------- shared rank+emit helper ----------------------------------
__device__ __forceinline__ void rank_emit(
    const u64 key, const uint32_t bin, const uint32_t* rcur,
    const uint32_t* rh, const u64* buf2, const float* boxes, float* out,
    const int n, const float s0, const float s1) {
  const uint32_t end = rcur[bin];          // start[bin] + count[bin]
  const uint32_t beg = end - rh[bin];
  uint32_t rank = beg;                     // #keys in strictly-higher bins
  for (uint32_t q = beg; q < end; ++q) rank += (uint32_t)(buf2[q] > key);
  if (rank < TOPK) {
    const uint32_t u = (uint32_t)(key >> 32);
    const uint32_t idx = ~(uint32_t)(key & 0xffffffffu);
    const float lgv = unordf(u);
    const float score = 1.0f / (1.0f + expf(-lgv));
    const uint32_t q = idx / NCLS;
    const uint32_t lab = idx - q * NCLS;
    const float4 b4 = *(const float4*)(boxes + ((size_t)n * NQ + q) * 4);
    float* op = out + ((size_t)n * TOPK + rank) * 6;  // 8-byte aligned
    float2* op2 = (float2*)op;
    op2[0] = make_float2((float)lab, score);
    op2[1] = make_float2((b4.x - 0.5f * b4.z) * s1, (b4.y - 0.5f * b4.w) * s0);
    op2[2] = make_float2(b4.z * s1, b4.w * s0);
  }
}

// ---------------- K2: rank + emit (fallback: radix re-reading logits) ------
__global__ __launch_bounds__(THREADS) void rank_kernel(
    const float* __restrict__ logits, const float* __restrict__ boxes,
    const int* __restrict__ osz, float* __restrict__ out,
    const u64* __restrict__ cand, const uint32_t* __restrict__ cnts) {
  __shared__ u64 buf[CAP];       // 16 KB: fallback compaction buffer
  __shared__ u64 smem64[4096];   // 32 KB: fallback hist4 | {buf2, rh, rcur}
  __shared__ uint32_t histf[NB]; // 8 KB: fallback prefix only
  __shared__ uint32_t sh_sel[3];
  __shared__ uint32_t sh_cnt;

  uint32_t* const hist4 = (uint32_t*)smem64;        // 8192 u32 (fallback)
  u64* const buf2 = smem64;                         // 2048 u64 (rank scatter)
  uint32_t* const rh = (uint32_t*)(smem64 + 2048);  // 512 u32 (bin counts)
  uint32_t* const rcur = (uint32_t*)(smem64 + 2304);// 512 u32 (start/cursor)

  const int n = blockIdx.x;
  const int t = threadIdx.x;
  const float* lg = logits + (size_t)n * QK;

  if (t < RNB) rh[t] = 0;

  uint32_t cnt = cnts[n];
  const bool fast_ok = (cnt >= TOPK && cnt <= CAP);  // block-uniform
  uint32_t baseord = ordf(T0F);

  u64 k0 = 0, k1 = 0;
  if (fast_ok) {
    const u64* cnd = cand + (size_t)n * CAP;
    if ((uint32_t)t < cnt) k0 = cnd[t];
    if ((uint32_t)(t + THREADS) < cnt) k1 = cnd[t + THREADS];
    __syncthreads();  // rh init visible
  } else {
    // ---- fallback: full radix select on ord(logit), then recompact to LDS.
    // Correct for arbitrary inputs; never taken for the bench distribution.
    __syncthreads();
    uint32_t T = 0, S_above = 0, Krem = TOPK;
    int prev_shift = 32;
    const uint32_t sub = (uint32_t)(t & 3);
    const int shifts[3] = {21, 10, 0};
    const int nbns[3] = {2048, 2048, 1024};

    for (int lvl = 0; lvl < 3; ++lvl) {
      const int sh = shifts[lvl];
      const uint32_t nb = (uint32_t)nbns[lvl];

      for (int b = t; b < NB * 4; b += THREADS) hist4[b] = 0;
      __syncthreads();
      for (int j = 0; j < 20; ++j) {
        if (j == 19 && t >= LAST_VALID) break;
        const int i = 4 * t + 4096 * j;
        const float4 v = *(const float4*)(lg + i);
        const float vs[4] = {v.x, v.y, v.z, v.w};
        for (int c = 0; c < 4; ++c) {
          const uint32_t u = ordf(vs[c]);
          if (lvl == 0 || (u >> prev_shift) == (T >> prev_shift))
            atomicAdd(&hist4[(((u >> sh) & (nb - 1)) << 2) | sub], 1u);
        }
      }
      __syncthreads();

      for (uint32_t b = t; b < nb; b += (uint32_t)THREADS) {
        const uint32_t i4 = b << 2;
        histf[b] = hist4[i4] + hist4[i4 + 1] + hist4[i4 + 2] + hist4[i4 + 3];
      }
      __syncthreads();

      for (uint32_t off = 1; off < nb; off <<= 1) {
        uint32_t a0 = histf[t] + ((t + off < nb) ? histf[t + off] : 0u);
        uint32_t a1 = 0;
        if (nb > (uint32_t)THREADS) {
          const uint32_t i1 = (uint32_t)t + THREADS;
          a1 = histf[i1] + ((i1 + off < nb) ? histf[i1 + off] : 0u);
        }
        __syncthreads();
        histf[t] = a0;
        if (nb > (uint32_t)THREADS) histf[(uint32_t)t + THREADS] = a1;
        __syncthreads();
      }

      for (uint32_t b = t; b < nb; b += (uint32_t)THREADS) {
        const uint32_t s = histf[b];
        const uint32_t sn = (b + 1 < nb) ? histf[b + 1] : 0u;
        if (s >= Krem && sn < Krem) {
          sh_sel[0] = b;
          sh_sel[1] = sn;
          sh_sel[2] = s;
        }
      }
      __syncthreads();
      const uint32_t bsel = sh_sel[0], above = sh_sel[1], candL = sh_sel[2];
      __syncthreads();

      T |= bsel << sh;
      if (S_above + candL <= CAP || lvl == 2) break;
      S_above += above;
      Krem -= above;
      prev_shift = sh;
    }

    // recompact with the radix-derived ordered threshold; re-zero rank bins
    if (t == 0) sh_cnt = 0;
    __syncthreads();
    if (t < RNB) rh[t] = 0;
    for (int j = 0; j < 20; ++j) {
      if (j == 19 && t >= LAST_VALID) break;
      const int i = 4 * t + 4096 * j;
      const float4 v = *(const float4*)(lg + i);
      const float vs[4] = {v.x, v.y, v.z, v.w};
      for (int c = 0; c < 4; ++c) {
        const uint32_t u = ordf(vs[c]);
        if (u >= T) {
          const uint32_t p = atomicAdd(&sh_cnt, 1u);
          if (p < CAP) buf[p] = mkkey(u, (uint32_t)(i + c));
        }
      }
    }
    __syncthreads();
    cnt = sh_cnt < CAP ? sh_cnt : CAP;
    baseord = T;  // all compacted keys have ord >= T
    if ((uint32_t)t < cnt) k0 = buf[t];
    if ((uint32_t)(t + THREADS) < cnt) k1 = buf[t + THREADS];
  }

  // ---- rank via monotone 512-bin histogram on (ord - baseord) >> RSH.
  // bin(a) > bin(b)  =>  a > b  (strict), so
  // rank(key) = (#keys in higher bins) + (#same-bin keys > key)  -- exact.
  uint32_t b0 = 0, b1 = 0;
  if ((uint32_t)t < cnt) {
    b0 = ((uint32_t)(k0 >> 32) - baseord) >> RSH;
    if (b0 > RNB - 1u) b0 = RNB - 1u;
    atomicAdd(&rh[b0], 1u);
  }
  if ((uint32_t)(t + THREADS) < cnt) {
    b1 = ((uint32_t)(k1 >> 32) - baseord) >> RSH;
    if (b1 > RNB - 1u) b1 = RNB - 1u;
    atomicAdd(&rh[b1], 1u);
  }
  __syncthreads();

  // ---- single-wave suffix scan: rcur[b] = sum_{b' > b} rh[b']  (start[b])
  if (t < 64) {
    const uint4 a = *(const uint4*)&rh[8 * t];
    const uint4 b = *(const uint4*)&rh[8 * t + 4];
    const uint32_t c0 = a.x, c1 = a.y, c2 = a.z, c3 = a.w;
    const uint32_t c4 = b.x, c5 = b.y, c6 = b.z, c7 = b.w;
    const uint32_t mysum = c0 + c1 + c2 + c3 + c4 + c5 + c6 + c7;
    uint32_t s = mysum;  // inclusive suffix over lanes
    for (int d = 1; d < 64; d <<= 1) {
      const uint32_t o = __shfl_down(s, d);
      if (t + d < 64) s += o;
    }
    uint32_t acc = s - mysum;  // sum over lanes > t
    rcur[8 * t + 7] = acc; acc += c7;
    rcur[8 * t + 6] = acc; acc += c6;
    rcur[8 * t + 5] = acc; acc += c5;
    rcur[8 * t + 4] = acc; acc += c4;
    rcur[8 * t + 3] = acc; acc += c3;
    rcur[8 * t + 2] = acc; acc += c2;
    rcur[8 * t + 1] = acc; acc += c1;
    rcur[8 * t + 0] = acc;
  }
  __syncthreads();

  // ---- scatter candidates into bin-ordered slots of buf2
  if ((uint32_t)t < cnt) {
    const uint32_t s = atomicAdd(&rcur[b0], 1u);
    buf2[s] = k0;
  }
  if ((uint32_t)(t + THREADS) < cnt) {
    const uint32_t s = atomicAdd(&rcur[b1], 1u);
    buf2[s] = k1;
  }
  __syncthreads();
  // now rcur[b] = start[b] + rh[b] = segment end for bin b

  const float s0 = (float)osz[0];
  const float s1 = (float)osz[1];

  if ((uint32_t)t < cnt)
    rank_emit(k0, b0, rcur, rh, buf2, boxes, out, n, s0, s1);
  if ((uint32_t)(t + THREADS) < cnt)
    rank_emit(k1, b1, rcur, rh, buf2, boxes, out, n, s0, s1);
}

// ---------------- monolithic R6 kernel: used only if ws too small ----------
__global__ __launch_bounds__(THREADS) void detr_post_mono(
    const float* __restrict__ logits, const float* __restrict__ boxes,
    const int* __restrict__ osz, float* __restrict__ out) {
  __shared__ u64 buf[CAP];
  __shared__ u64 smem64[4096];
  __shared__ uint32_t histf[NB];
  __shared__ uint32_t sh_sel[3];
  __shared__ uint32_t sh_cnt;

  uint32_t* const hist4 = (uint32_t*)smem64;
  u64* const buf2 = smem64;
  uint32_t* const rh = (uint32_t*)(smem64 + 2048);
  uint32_t* const rcur = (uint32_t*)(smem64 + 2304);

  const int n = blockIdx.x;
  const int t = threadIdx.x;
  const float* lg = logits + (size_t)n * QK;

  if (t == 0) sh_cnt = 0;
  if (t < RNB) rh[t] = 0;
  __syncthreads();

#pragma unroll 5
  for (int j = 0; j < 19; ++j) {
    const int i = 4 * t + 4096 * j;
    const float4 v = *(const float4*)(lg + i);
    if (v.x >= T0F) {
      const uint32_t p = atomicAdd(&sh_cnt, 1u);
      if (p < CAP) buf[p] = mkkey(ordf(v.x), (uint32_t)(i + 0));
    }
    if (v.y >= T0F) {
      const uint32_t p = atomicAdd(&sh_cnt, 1u);
      if (p < CAP) buf[p] = mkkey(ordf(v.y), (uint32_t)(i + 1));
    }
    if (v.z >= T0F) {
      const uint32_t p = atomicAdd(&sh_cnt, 1u);
      if (p < CAP) buf[p] = mkkey(ordf(v.z), (uint32_t)(i + 2));
    }
    if (v.w >= T0F) {
      const uint32_t p = atomicAdd(&sh_cnt, 1u);
      if (p < CAP) buf[p] = mkkey(ordf(v.w), (uint32_t)(i + 3));
    }
  }
  if (t < LAST_VALID) {
    const int i = 4 * t + 4096 * 19;
    const float4 v = *(const float4*)(lg + i);
    if (v.x >= T0F) {
      const uint32_t p = atomicAdd(&sh_cnt, 1u);
      if (p < CAP) buf[p] = mkkey(ordf(v.x), (uint32_t)(i + 0));
    }
    if (v.y >= T0F) {
      const uint32_t p = atomicAdd(&sh_cnt, 1u);
      if (p < CAP) buf[p] = mkkey(ordf(v.y), (uint32_t)(i + 1));
    }
    if (v.z >= T0F) {
      const uint32_t p = atomicAdd(&sh_cnt, 1u);
      if (p < CAP) buf[p] = mkkey(ordf(v.z), (uint32_t)(i + 2));
    }
    if (v.w >= T0F) {
      const uint32_t p = atomicAdd(&sh_cnt, 1u);
      if (p < CAP) buf[p] = mkkey(ordf(v.w), (uint32_t)(i + 3));
    }
  }
  __syncthreads();

  uint32_t cnt = sh_cnt;
  const bool fast_ok = (cnt >= TOPK && cnt <= CAP);
  uint32_t baseord = ordf(T0F);

  if (!fast_ok) {
    uint32_t T = 0, S_above = 0, Krem = TOPK;
    int prev_shift = 32;
    const uint32_t sub = (uint32_t)(t & 3);
    const int shifts[3] = {21, 10, 0};
    const int nbns[3] = {2048, 2048, 1024};

    for (int lvl = 0; lvl < 3; ++lvl) {
      const int sh = shifts[lvl];
      const uint32_t nb = (uint32_t)nbns[lvl];

      for (int b = t; b < NB * 4; b += THREADS) hist4[b] = 0;
      __syncthreads();
      for (int j = 0; j < 20; ++j) {
        if (j == 19 && t >= LAST_VALID) break;
        const int i = 4 * t + 4096 * j;
        const float4 v = *(const float4*)(lg + i);
        const float vs[4] = {v.x, v.y, v.z, v.w};
        for (int c = 0; c < 4; ++c) {
          const uint32_t u = ordf(vs[c]);
          if (lvl == 0 || (u >> prev_shift) == (T >> prev_shift))
            atomicAdd(&hist4[(((u >> sh) & (nb - 1)) << 2) | sub], 1u);
        }
      }
      __syncthreads();

      for (uint32_t b = t; b < nb; b += (uint32_t)THREADS) {
        const uint32_t i4 = b << 2;
        histf[b] = hist4[i4] + hist4[i4 + 1] + hist4[i4 + 2] + hist4[i4 + 3];
      }
      __syncthreads();

      for (uint32_t off = 1; off < nb; off <<= 1) {
        uint32_t a0 = histf[t] + ((t + off < nb) ? histf[t + off] : 0u);
        uint32_t a1 = 0;
        if (nb > (uint32_t)THREADS) {
          const uint32_t i1 = (uint32_t)t + THREADS;
          a1 = histf[i1] + ((i1 + off < nb) ? histf[i1 + off] : 0u);
        }
        __syncthreads();
        histf[t] = a0;
        if (nb > (uint32_t)THREADS) histf[(uint32_t)t + THREADS] = a1;
        __syncthreads();
      }

      for (uint32_t b = t; b < nb; b += (uint32_t)THREADS) {
        const uint32_t s = histf[b];
        const uint32_t sn = (b + 1 < nb) ? histf[b + 1] : 0u;
        if (s >= Krem && sn < Krem) {
          sh_sel[0] = b;
          sh_sel[1] = sn;
          sh_sel[2] = s;
        }
      }
      __syncthreads();
      const uint32_t bsel = sh_sel[0], above = sh_sel[1], candL = sh_sel[2];
      __syncthreads();

      T |= bsel << sh;
      if (S_above + candL <= CAP || lvl == 2) break;
      S_above += above;
      Krem -= above;
      prev_shift = sh;
    }

    if (t == 0) sh_cnt = 0;
    __syncthreads();
    if (t < RNB) rh[t] = 0;
    for (int j = 0; j < 20; ++j) {
      if (j == 19 && t >= LAST_VALID) break;
      const int i = 4 * t + 4096 * j;
      const float4 v = *(const float4*)(lg + i);
      const float vs[4] = {v.x, v.y, v.z, v.w};
      for (int c = 0; c < 4; ++c) {
        const uint32_t u = ordf(vs[c]);
        if (u >= T) {
          const uint32_t p = atomicAdd(&sh_cnt, 1u);
          if (p < CAP) buf[p] = mkkey(u, (uint32_t)(i + c));
        }
      }
    }
    __syncthreads();
    cnt = sh_cnt < CAP ? sh_cnt : CAP;
    baseord = T;
  }

  const u64 k0 = ((uint32_t)t < cnt) ? buf[t] : 0ULL;
  const u64 k1 = ((uint32_t)(t + THREADS) < cnt) ? buf[t + THREADS] : 0ULL;
  uint32_t b0 = 0, b1 = 0;
  if ((uint32_t)t < cnt) {
    b0 = ((uint32_t)(k0 >> 32) - baseord) >> RSH;
    if (b0 > RNB - 1u) b0 = RNB - 1u;
    atomicAdd(&rh[b0], 1u);
  }
  if ((uint32_t)(t + THREADS) < cnt) {
    b1 = ((uint32_t)(k1 >> 32) - baseord) >> RSH;
    if (b1 > RNB - 1u) b1 = RNB - 1u;
    atomicAdd(&rh[b1], 1u);
  }
  __syncthreads();

  if (t < 64) {
    const uint4 a = *(const uint4*)&rh[8 * t];
    const uint4 b = *(const uint4*)&rh[8 * t + 4];
    const uint32_t c0 = a.x, c1 = a.y, c2 = a.z, c3 = a.w;
    const uint32_t c4 = b.x, c5 = b.y, c6 = b.z, c7 = b.w;
    const uint32_t mysum = c0 + c1 + c2 + c3 + c4 + c5 + c6 + c7;
    uint32_t s = mysum;
    for (int d = 1; d < 64; d <<= 1) {
      const uint32_t o = __shfl_down(s, d);
      if (t + d < 64) s += o;
    }
    uint32_t acc = s - mysum;
    rcur[8 * t + 7] = acc; acc += c7;
    rcur[8 * t + 6] = acc; acc += c6;
    rcur[8 * t + 5] = acc; acc += c5;
    rcur[8 * t + 4] = acc; acc += c4;
    rcur[8 * t + 3] = acc; acc += c3;
    rcur[8 * t + 2] = acc; acc += c2;
    rcur[8 * t + 1] = acc; acc += c1;
    rcur[8 * t + 0] = acc;
  }
  __syncthreads();

  if ((uint32_t)t < cnt) {
    const uint32_t s = atomicAdd(&rcur[b0], 1u);
    buf2[s] = k0;
  }
  if ((uint32_t)(t + THREADS) < cnt) {
    const uint32_t s = atomicAdd(&rcur[b1], 1u);
    buf2[s] = k1;
  }
  __syncthreads();

  const float s0 = (float)osz[0];
  const float s1 = (float)osz[1];

  if ((uint32_t)t < cnt)
    rank_emit(k0, b0, rcur, rh, buf2, boxes, out, n, s0, s1);
  if ((uint32_t)(t + THREADS) < cnt)
    rank_emit(k1, b1, rcur, rh, buf2, boxes, out, n, s0, s1);
}

extern "C" void kernel_launch(void* const* d_in, const int* in_sizes, int n_in,
                              void* d_out, int out_size, void* d_ws, size_t ws_size,
                              hipStream_t stream) {
  const float* logits = (const float*)d_in[0];
  const float* boxes = (const float*)d_in[1];
  const int* osz = (const int*)d_in[2];
  float* out = (float*)d_out;
  const int nbatch = in_sizes[0] / QK;  // 256

  // ws layout: [cnts: nbatch u32, padded to 1024 B][cand: nbatch*CAP u64]
  const size_t cnt_bytes = 1024;
  const size_t need = cnt_bytes + (size_t)nbatch * CAP * sizeof(u64);
  if (d_ws != nullptr && ws_size >= need && (size_t)nbatch * 4 <= cnt_bytes) {
    uint32_t* cnts = (uint32_t*)d_ws;
    u64* cand = (u64*)((char*)d_ws + cnt_bytes);
    const int zblocks = (nbatch + STHREADS - 1) / STHREADS;
    zero_kernel<<<zblocks, STHREADS, 0, stream>>>(cnts, nbatch);
    scan_kernel<<<nbatch * SBLK, STHREADS, 0, stream>>>(logits, cand, cnts);
    rank_kernel<<<nbatch, THREADS, 0, stream>>>(logits, boxes, osz, out, cand,
                                                cnts);
  } else {
    detr_post_mono<<<nbatch, THREADS, 0, stream>>>(logits, boxes, osz, out);
  }
}

// Round 6
// 125.070 us; speedup vs baseline: 2.1098x; 1.0071x over previous
//
#include <hip/hip_runtime.h>
#include <stdint.h>

// DETR post-process: per batch n of 256, top-300 of sigmoid(logits[n]) (80000
// elems), output [label, score, scaled box] per selected query.
//
// Ordering: jax top_k = score desc, tie -> lowest index. sigmoid is strictly
// monotonic, so we rank on 64-bit key (ord(logit)<<32 | ~index): descending
// key order == (score desc, index asc) exactly.
//
// R10 structure: TWO kernels through d_ws, zero cross-block coupling.
//   K1 (scan): 8 blocks/batch x 256 threads (8 blocks/CU = 32 waves/CU).
//     Each block owns an EXCLUSIVE 256-slot slice of the batch's candidate
//     array: LDS counter allocates slots, candidates >= 2.4f stored directly
//     to global (~82 scattered 8B stores/block), TRUE count written
//     non-atomically to the block's own cnt8 slot. Every cnt8 slot is
//     rewritten every launch -> no zero kernel, no stale state.
//     R8 LESSON: per-candidate global atomics = 161 us. R9 LESSON: zero
//     kernel + global counter atomic + LDS staging + 3 dispatches ate the
//     occupancy win (~27 us of kernel for a 13 us floor).
//   K2 (rank): one 1024-thread block per batch. Fast path iff total in
//     [TOPK, CAP] AND every slice count <= 256: slot validity is the pure
//     predicate (t&255) < c8[t>>8] (rank ignores candidate order, so no
//     gather/prefix). Monotone 512-bin histogram rank (single-wave shfl
//     suffix scan), scatter, exact within-bin tie count, emit. Otherwise:
//     full radix-select fallback re-reading logits (arbitrary-data correct,
//     never taken for the bench distribution).
//   If ws_size too small: monolithic R6 kernel fallback.
//
// Hard-learned rules: NO per-thread arrays with runtime indexing (R2/R3:
// scratch spill) -> slice counts live in LDS. All load indices compile-time
// affine. No per-candidate global atomics (R8). No avoidable dispatches (R9).

#define TOPK 300
#define NCLS 80
#define NQ 1000
#define QK (NQ * NCLS)   // 80000
#define NB 2048          // fallback radix bins
#define CAP 2048
#define THREADS 1024
#define LAST_VALID 544   // j=19: 4*t + 4096*19 < 80000  <=>  t < 544
#define T0F 2.4f         // fixed fast-path threshold (z-score)
#define RNB 512          // rank bins
#define RSH 14           // rank-bin shift: bin = (ord - base) >> RSH

// K1 geometry: 8 blocks per batch, 256 threads, 10000 floats (2500 float4)
// per block; j=0..8 full, j=9 partial (t < 196). Slice = 256 slots
// (bench count ~82 +- 9 -> 19 sigma below cap).
#define SBLK 8
#define STHREADS 256
#define SCHUNK 10000
#define SLAST 196
#define SLICE 256

typedef unsigned long long u64;

__device__ __forceinline__ uint32_t ordf(float f) {
  uint32_t u = __float_as_uint(f);
  return (u & 0x80000000u) ? ~u : (u | 0x80000000u);  // monotonic float->uint
}
__device__ __forceinline__ float unordf(uint32_t o) {
  uint32_t u = (o & 0x80000000u) ? (o & 0x7fffffffu) : ~o;
  return __uint_as_float(u);
}
__device__ __forceinline__ u64 mkkey(uint32_t ord, uint32_t idx) {
  return ((u64)ord << 32) | (u64)(~idx);
}

// ---------------- K1: streaming scan -> exclusive per-block slice ----------
__global__ __launch_bounds__(STHREADS) void scan_kernel(
    const float* __restrict__ logits, u64* __restrict__ cand,
    uint32_t* __restrict__ cnt8) {
  __shared__ uint32_t lcnt;

  const int n = blockIdx.x >> 3;        // batch
  const int rb = blockIdx.x & 7;        // chunk within batch
  const int t = threadIdx.x;
  const int coff = rb * SCHUNK;
  const float* lg = logits + (size_t)n * QK + coff;
  u64* slice = cand + (size_t)n * CAP + (size_t)rb * SLICE;

  if (t == 0) lcnt = 0;
  __syncthreads();

#pragma unroll
  for (int j = 0; j < 10; ++j) {
    if (j == 9 && t >= SLAST) break;
    const int i = 4 * (t + STHREADS * j);
    const float4 v = *(const float4*)(lg + i);
    const int gi = coff + i;
    if (v.x >= T0F) {
      const uint32_t p = atomicAdd(&lcnt, 1u);
      if (p < SLICE) slice[p] = mkkey(ordf(v.x), (uint32_t)(gi + 0));
    }
    if (v.y >= T0F) {
      const uint32_t p = atomicAdd(&lcnt, 1u);
      if (p < SLICE) slice[p] = mkkey(ordf(v.y), (uint32_t)(gi + 1));
    }
    if (v.z >= T0F) {
      const uint32_t p = atomicAdd(&lcnt, 1u);
      if (p < SLICE) slice[p] = mkkey(ordf(v.z), (uint32_t)(gi + 2));
    }
    if (v.w >= T0F) {
      const uint32_t p = atomicAdd(&lcnt, 1u);
      if (p < SLICE) slice[p] = mkkey(ordf(v.w), (uint32_t)(gi + 3));
    }
  }
  __syncthreads();
  if (t == 0) cnt8[n * 8 + rb] = lcnt;  // TRUE count (may exceed SLICE)
}

// ---------------- shared rank+emit helper ----------------------------------
__device__ __forceinline__ void rank_emit(
    const u64 key, const uint32_t bin, const uint32_t* rcur,
    const uint32_t* rh, const u64* buf2, const float* boxes, float* out,
    const int n, const float s0, const float s1) {
  const uint32_t end = rcur[bin];          // start[bin] + count[bin]
  const uint32_t beg = end - rh[bin];
  uint32_t rank = beg;                     // #keys in strictly-higher bins
  for (uint32_t q = beg; q < end; ++q) rank += (uint32_t)(buf2[q] > key);
  if (rank < TOPK) {
    const uint32_t u = (uint32_t)(key >> 32);
    const uint32_t idx = ~(uint32_t)(key & 0xffffffffu);
    const float lgv = unordf(u);
    const float score = 1.0f / (1.0f + expf(-lgv));
    const uint32_t q = idx / NCLS;
    const uint32_t lab = idx - q * NCLS;
    const float4 b4 = *(const float4*)(boxes + ((size_t)n * NQ + q) * 4);
    float* op = out + ((size_t)n * TOPK + rank) * 6;  // 8-byte aligned
    float2* op2 = (float2*)op;
    op2[0] = make_float2((float)lab, score);
    op2[1] = make_float2((b4.x - 0.5f * b4.z) * s1, (b4.y - 0.5f * b4.w) * s0);
    op2[2] = make_float2(b4.z * s1, b4.w * s0);
  }
}

// ---------------- K2: rank + emit (fallback: radix re-reading logits) ------
__global__ __launch_bounds__(THREADS) void rank_kernel(
    const float* __restrict__ logits, const float* __restrict__ boxes,
    const int* __restrict__ osz, float* __restrict__ out,
    const u64* __restrict__ cand, const uint32_t* __restrict__ cnt8) {
  __shared__ u64 buf[CAP];       // 16 KB: fallback compaction buffer
  __shared__ u64 smem64[4096];   // 32 KB: fallback hist4 | {buf2, rh, rcur}
  __shared__ uint32_t histf[NB]; // 8 KB: fallback prefix only
  __shared__ uint32_t sh_sel[3];
  __shared__ uint32_t sh_cnt;
  __shared__ uint32_t sh_c8[8];  // per-slice counts

  uint32_t* const hist4 = (uint32_t*)smem64;        // 8192 u32 (fallback)
  u64* const buf2 = smem64;                         // 2048 u64 (rank scatter)
  uint32_t* const rh = (uint32_t*)(smem64 + 2048);  // 512 u32 (bin counts)
  uint32_t* const rcur = (uint32_t*)(smem64 + 2304);// 512 u32 (start/cursor)

  const int n = blockIdx.x;
  const int t = threadIdx.x;
  const float* lg = logits + (size_t)n * QK;

  if (t < RNB) rh[t] = 0;
  if (t < 8) sh_c8[t] = cnt8[n * 8 + t];
  __syncthreads();

  const uint32_t c0 = sh_c8[0], c1 = sh_c8[1], c2 = sh_c8[2], c3 = sh_c8[3];
  const uint32_t c4 = sh_c8[4], c5 = sh_c8[5], c6 = sh_c8[6], c7 = sh_c8[7];
  const uint32_t tot = c0 + c1 + c2 + c3 + c4 + c5 + c6 + c7;
  const uint32_t cmax =
      max(max(max(c0, c1), max(c2, c3)), max(max(c4, c5), max(c6, c7)));
  const bool fast_ok =
      (tot >= TOPK && tot <= CAP && cmax <= SLICE);  // block-uniform

  uint32_t baseord = ordf(T0F);
  u64 k0 = 0, k1 = 0;
  bool valid0 = false, valid1 = false;

  if (fast_ok) {
    // slot t -> slice t>>8, offset t&255; valid iff offset < slice count.
    // rank ignores candidate order, so validity predicate replaces gather.
    valid0 = (uint32_t)(t & 255) < sh_c8[t >> 8];
    valid1 = (uint32_t)(t & 255) < sh_c8[(t >> 8) + 4];
    const u64* cnd = cand + (size_t)n * CAP;
    if (valid0) k0 = cnd[t];
    if (valid1) k1 = cnd[t + THREADS];
  } else {
    // ---- fallback: full radix select on ord(logit), then recompact to LDS.
    // Correct for arbitrary inputs; never taken for the bench distribution.
    uint32_t T = 0, S_above = 0, Krem = TOPK;
    int prev_shift = 32;
    const uint32_t sub = (uint32_t)(t & 3);
    const int shifts[3] = {21, 10, 0};
    const int nbns[3] = {2048, 2048, 1024};

    for (int lvl = 0; lvl < 3; ++lvl) {
      const int sh = shifts[lvl];
      const uint32_t nb = (uint32_t)nbns[lvl];

      for (int b = t; b < NB * 4; b += THREADS) hist4[b] = 0;
      __syncthreads();
      for (int j = 0; j < 20; ++j) {
        if (j == 19 && t >= LAST_VALID) break;
        const int i = 4 * t + 4096 * j;
        const float4 v = *(const float4*)(lg + i);
        const float vs[4] = {v.x, v.y, v.z, v.w};
        for (int c = 0; c < 4; ++c) {
          const uint32_t u = ordf(vs[c]);
          if (lvl == 0 || (u >> prev_shift) == (T >> prev_shift))
            atomicAdd(&hist4[(((u >> sh) & (nb - 1)) << 2) | sub], 1u);
        }
      }
      __syncthreads();

      for (uint32_t b = t; b < nb; b += (uint32_t)THREADS) {
        const uint32_t i4 = b << 2;
        histf[b] = hist4[i4] + hist4[i4 + 1] + hist4[i4 + 2] + hist4[i4 + 3];
      }
      __syncthreads();

      for (uint32_t off = 1; off < nb; off <<= 1) {
        uint32_t a0 = histf[t] + ((t + off < nb) ? histf[t + off] : 0u);
        uint32_t a1 = 0;
        if (nb > (uint32_t)THREADS) {
          const uint32_t i1 = (uint32_t)t + THREADS;
          a1 = histf[i1] + ((i1 + off < nb) ? histf[i1 + off] : 0u);
        }
        __syncthreads();
        histf[t] = a0;
        if (nb > (uint32_t)THREADS) histf[(uint32_t)t + THREADS] = a1;
        __syncthreads();
      }

      for (uint32_t b = t; b < nb; b += (uint32_t)THREADS) {
        const uint32_t s = histf[b];
        const uint32_t sn = (b + 1 < nb) ? histf[b + 1] : 0u;
        if (s >= Krem && sn < Krem) {
          sh_sel[0] = b;
          sh_sel[1] = sn;
          sh_sel[2] = s;
        }
      }
      __syncthreads();
      const uint32_t bsel = sh_sel[0], above = sh_sel[1], candL = sh_sel[2];
      __syncthreads();

      T |= bsel << sh;
      if (S_above + candL <= CAP || lvl == 2) break;
      S_above += above;
      Krem -= above;
      prev_shift = sh;
    }

    // recompact with the radix-derived ordered threshold; re-zero rank bins
    if (t == 0) sh_cnt = 0;
    __syncthreads();
    if (t < RNB) rh[t] = 0;
    for (int j = 0; j < 20; ++j) {
      if (j == 19 && t >= LAST_VALID) break;
      const int i = 4 * t + 4096 * j;
      const float4 v = *(const float4*)(lg + i);
      const float vs[4] = {v.x, v.y, v.z, v.w};
      for (int c = 0; c < 4; ++c) {
        const uint32_t u = ordf(vs[c]);
        if (u >= T) {
          const uint32_t p = atomicAdd(&sh_cnt, 1u);
          if (p < CAP) buf[p] = mkkey(u, (uint32_t)(i + c));
        }
      }
    }
    __syncthreads();
    const uint32_t cnt = sh_cnt < CAP ? sh_cnt : CAP;
    baseord = T;  // all compacted keys have ord >= T
    valid0 = (uint32_t)t < cnt;
    valid1 = (uint32_t)(t + THREADS) < cnt;
    if (valid0) k0 = buf[t];
    if (valid1) k1 = buf[t + THREADS];
  }

  // ---- rank via monotone 512-bin histogram on (ord - baseord) >> RSH.
  // bin(a) > bin(b)  =>  a > b  (strict), so
  // rank(key) = (#keys in higher bins) + (#same-bin keys > key)  -- exact.
  uint32_t b0 = 0, b1 = 0;
  if (valid0) {
    b0 = ((uint32_t)(k0 >> 32) - baseord) >> RSH;
    if (b0 > RNB - 1u) b0 = RNB - 1u;
    atomicAdd(&rh[b0], 1u);
  }
  if (valid1) {
    b1 = ((uint32_t)(k1 >> 32) - baseord) >> RSH;
    if (b1 > RNB - 1u) b1 = RNB - 1u;
    atomicAdd(&rh[b1], 1u);
  }
  __syncthreads();

  // ---- single-wave suffix scan: rcur[b] = sum_{b' > b} rh[b']  (start[b])
  if (t < 64) {
    const uint4 a = *(const uint4*)&rh[8 * t];
    const uint4 b = *(const uint4*)&rh[8 * t + 4];
    const uint32_t d0 = a.x, d1 = a.y, d2 = a.z, d3 = a.w;
    const uint32_t d4 = b.x, d5 = b.y, d6 = b.z, d7 = b.w;
    const uint32_t mysum = d0 + d1 + d2 + d3 + d4 + d5 + d6 + d7;
    uint32_t s = mysum;  // inclusive suffix over lanes
    for (int d = 1; d < 64; d <<= 1) {
      const uint32_t o = __shfl_down(s, d);
      if (t + d < 64) s += o;
    }
    uint32_t acc = s - mysum;  // sum over lanes > t
    rcur[8 * t + 7] = acc; acc += d7;
    rcur[8 * t + 6] = acc; acc += d6;
    rcur[8 * t + 5] = acc; acc += d5;
    rcur[8 * t + 4] = acc; acc += d4;
    rcur[8 * t + 3] = acc; acc += d3;
    rcur[8 * t + 2] = acc; acc += d2;
    rcur[8 * t + 1] = acc; acc += d1;
    rcur[8 * t + 0] = acc;
  }
  __syncthreads();

  // ---- scatter candidates into bin-ordered slots of buf2
  if (valid0) {
    const uint32_t s = atomicAdd(&rcur[b0], 1u);
    buf2[s] = k0;
  }
  if (valid1) {
    const uint32_t s = atomicAdd(&rcur[b1], 1u);
    buf2[s] = k1;
  }
  __syncthreads();
  // now rcur[b] = start[b] + rh[b] = segment end for bin b

  const float s0 = (float)osz[0];
  const float s1 = (float)osz[1];

  if (valid0) rank_emit(k0, b0, rcur, rh, buf2, boxes, out, n, s0, s1);
  if (valid1) rank_emit(k1, b1, rcur, rh, buf2, boxes, out, n, s0, s1);
}

// ---------------- monolithic R6 kernel: used only if ws too small ----------
__global__ __launch_bounds__(THREADS) void detr_post_mono(
    const float* __restrict__ logits, const float* __restrict__ boxes,
    const int* __restrict__ osz, float* __restrict__ out) {
  __shared__ u64 buf[CAP];
  __shared__ u64 smem64[4096];
  __shared__ uint32_t histf[NB];
  __shared__ uint32_t sh_sel[3];
  __shared__ uint32_t sh_cnt;

  uint32_t* const hist4 = (uint32_t*)smem64;
  u64* const buf2 = smem64;
  uint32_t* const rh = (uint32_t*)(smem64 + 2048);
  uint32_t* const rcur = (uint32_t*)(smem64 + 2304);

  const int n = blockIdx.x;
  const int t = threadIdx.x;
  const float* lg = logits + (size_t)n * QK;

  if (t == 0) sh_cnt = 0;
  if (t < RNB) rh[t] = 0;
  __syncthreads();

#pragma unroll 5
  for (int j = 0; j < 19; ++j) {
    const int i = 4 * t + 4096 * j;
    const float4 v = *(const float4*)(lg + i);
    if (v.x >= T0F) {
      const uint32_t p = atomicAdd(&sh_cnt, 1u);
      if (p < CAP) buf[p] = mkkey(ordf(v.x), (uint32_t)(i + 0));
    }
    if (v.y >= T0F) {
      const uint32_t p = atomicAdd(&sh_cnt, 1u);
      if (p < CAP) buf[p] = mkkey(ordf(v.y), (uint32_t)(i + 1));
    }
    if (v.z >= T0F) {
      const uint32_t p = atomicAdd(&sh_cnt, 1u);
      if (p < CAP) buf[p] = mkkey(ordf(v.z), (uint32_t)(i + 2));
    }
    if (v.w >= T0F) {
      const uint32_t p = atomicAdd(&sh_cnt, 1u);
      if (p < CAP) buf[p] = mkkey(ordf(v.w), (uint32_t)(i + 3));
    }
  }
  if (t < LAST_VALID) {
    const int i = 4 * t + 4096 * 19;
    const float4 v = *(const float4*)(lg + i);
    if (v.x >= T0F) {
      const uint32_t p = atomicAdd(&sh_cnt, 1u);
      if (p < CAP) buf[p] = mkkey(ordf(v.x), (uint32_t)(i + 0));
    }
    if (v.y >= T0F) {
      const uint32_t p = atomicAdd(&sh_cnt, 1u);
      if (p < CAP) buf[p] = mkkey(ordf(v.y), (uint32_t)(i + 1));
    }
    if (v.z >= T0F) {
      const uint32_t p = atomicAdd(&sh_cnt, 1u);
      if (p < CAP) buf[p] = mkkey(ordf(v.z), (uint32_t)(i + 2));
    }
    if (v.w >= T0F) {
      const uint32_t p = atomicAdd(&sh_cnt, 1u);
      if (p < CAP) buf[p] = mkkey(ordf(v.w), (uint32_t)(i + 3));
    }
  }
  __syncthreads();

  uint32_t cnt = sh_cnt;
  const bool fast_ok = (cnt >= TOPK && cnt <= CAP);
  uint32_t baseord = ordf(T0F);

  if (!fast_ok) {
    uint32_t T = 0, S_above = 0, Krem = TOPK;
    int prev_shift = 32;
    const uint32_t sub = (uint32_t)(t & 3);
    const int shifts[3] = {21, 10, 0};
    const int nbns[3] = {2048, 2048, 1024};

    for (int lvl = 0; lvl < 3; ++lvl) {
      const int sh = shifts[lvl];
      const uint32_t nb = (uint32_t)nbns[lvl];

      for (int b = t; b < NB * 4; b += THREADS) hist4[b] = 0;
      __syncthreads();
      for (int j = 0; j < 20; ++j) {
        if (j == 19 && t >= LAST_VALID) break;
        const int i = 4 * t + 4096 * j;
        const float4 v = *(const float4*)(lg + i);
        const float vs[4] = {v.x, v.y, v.z, v.w};
        for (int c = 0; c < 4; ++c) {
          const uint32_t u = ordf(vs[c]);
          if (lvl == 0 || (u >> prev_shift) == (T >> prev_shift))
            atomicAdd(&hist4[(((u >> sh) & (nb - 1)) << 2) | sub], 1u);
        }
      }
      __syncthreads();

      for (uint32_t b = t; b < nb; b += (uint32_t)THREADS) {
        const uint32_t i4 = b << 2;
        histf[b] = hist4[i4] + hist4[i4 + 1] + hist4[i4 + 2] + hist4[i4 + 3];
      }
      __syncthreads();

      for (uint32_t off = 1; off < nb; off <<= 1) {
        uint32_t a0 = histf[t] + ((t + off < nb) ? histf[t + off] : 0u);
        uint32_t a1 = 0;
        if (nb > (uint32_t)THREADS) {
          const uint32_t i1 = (uint32_t)t + THREADS;
          a1 = histf[i1] + ((i1 + off < nb) ? histf[i1 + off] : 0u);
        }
        __syncthreads();
        histf[t] = a0;
        if (nb > (uint32_t)THREADS) histf[(uint32_t)t + THREADS] = a1;
        __syncthreads();
      }

      for (uint32_t b = t; b < nb; b += (uint32_t)THREADS) {
        const uint32_t s = histf[b];
        const uint32_t sn = (b + 1 < nb) ? histf[b + 1] : 0u;
        if (s >= Krem && sn < Krem) {
          sh_sel[0] = b;
          sh_sel[1] = sn;
          sh_sel[2] = s;
        }
      }
      __syncthreads();
      const uint32_t bsel = sh_sel[0], above = sh_sel[1], candL = sh_sel[2];
      __syncthreads();

      T |= bsel << sh;
      if (S_above + candL <= CAP || lvl == 2) break;
      S_above += above;
      Krem -= above;
      prev_shift = sh;
    }

    if (t == 0) sh_cnt = 0;
    __syncthreads();
    if (t < RNB) rh[t] = 0;
    for (int j = 0; j < 20; ++j) {
      if (j == 19 && t >= LAST_VALID) break;
      const int i = 4 * t + 4096 * j;
      const float4 v = *(const float4*)(lg + i);
      const float vs[4] = {v.x, v.y, v.z, v.w};
      for (int c = 0; c < 4; ++c) {
        const uint32_t u = ordf(vs[c]);
        if (u >= T) {
          const uint32_t p = atomicAdd(&sh_cnt, 1u);
          if (p < CAP) buf[p] = mkkey(u, (uint32_t)(i + c));
        }
      }
    }
    __syncthreads();
    cnt = sh_cnt < CAP ? sh_cnt : CAP;
    baseord = T;
  }

  const u64 k0 = ((uint32_t)t < cnt) ? buf[t] : 0ULL;
  const u64 k1 = ((uint32_t)(t + THREADS) < cnt) ? buf[t + THREADS] : 0ULL;
  uint32_t b0 = 0, b1 = 0;
  if ((uint32_t)t < cnt) {
    b0 = ((uint32_t)(k0 >> 32) - baseord) >> RSH;
    if (b0 > RNB - 1u) b0 = RNB - 1u;
    atomicAdd(&rh[b0], 1u);
  }
  if ((uint32_t)(t + THREADS) < cnt) {
    b1 = ((uint32_t)(k1 >> 32) - baseord) >> RSH;
    if (b1 > RNB - 1u) b1 = RNB - 1u;
    atomicAdd(&rh[b1], 1u);
  }
  __syncthreads();

  if (t < 64) {
    const uint4 a = *(const uint4*)&rh[8 * t];
    const uint4 b = *(const uint4*)&rh[8 * t + 4];
    const uint32_t d0 = a.x, d1 = a.y, d2 = a.z, d3 = a.w;
    const uint32_t d4 = b.x, d5 = b.y, d6 = b.z, d7 = b.w;
    const uint32_t mysum = d0 + d1 + d2 + d3 + d4 + d5 + d6 + d7;
    uint32_t s = mysum;
    for (int d = 1; d < 64; d <<= 1) {
      const uint32_t o = __shfl_down(s, d);
      if (t + d < 64) s += o;
    }
    uint32_t acc = s - mysum;
    rcur[8 * t + 7] = acc; acc += d7;
    rcur[8 * t + 6] = acc; acc += d6;
    rcur[8 * t + 5] = acc; acc += d5;
    rcur[8 * t + 4] = acc; acc += d4;
    rcur[8 * t + 3] = acc; acc += d3;
    rcur[8 * t + 2] = acc; acc += d2;
    rcur[8 * t + 1] = acc; acc += d1;
    rcur[8 * t + 0] = acc;
  }
  __syncthreads();

  if ((uint32_t)t < cnt) {
    const uint32_t s = atomicAdd(&rcur[b0], 1u);
    buf2[s] = k0;
  }
  if ((uint32_t)(t + THREADS) < cnt) {
    const uint32_t s = atomicAdd(&rcur[b1], 1u);
    buf2[s] = k1;
  }
  __syncthreads();

  const float s0 = (float)osz[0];
  const float s1 = (float)osz[1];

  if ((uint32_t)t < cnt)
    rank_emit(k0, b0, rcur, rh, buf2, boxes, out, n, s0, s1);
  if ((uint32_t)(t + THREADS) < cnt)
    rank_emit(k1, b1, rcur, rh, buf2, boxes, out, n, s0, s1);
}

extern "C" void kernel_launch(void* const* d_in, const int* in_sizes, int n_in,
                              void* d_out, int out_size, void* d_ws, size_t ws_size,
                              hipStream_t stream) {
  const float* logits = (const float*)d_in[0];
  const float* boxes = (const float*)d_in[1];
  const int* osz = (const int*)d_in[2];
  float* out = (float*)d_out;
  const int nbatch = in_sizes[0] / QK;  // 256

  // ws layout: [cnt8: nbatch*8 u32 (8 KB)][cand: nbatch*CAP u64 (4 MB)]
  const size_t cnt_bytes = 8192;
  const size_t need = cnt_bytes + (size_t)nbatch * CAP * sizeof(u64);
  if (d_ws != nullptr && ws_size >= need &&
      (size_t)nbatch * 8 * 4 <= cnt_bytes) {
    uint32_t* cnt8 = (uint32_t*)d_ws;
    u64* cand = (u64*)((char*)d_ws + cnt_bytes);
    scan_kernel<<<nbatch * SBLK, STHREADS, 0, stream>>>(logits, cand, cnt8);
    rank_kernel<<<nbatch, THREADS, 0, stream>>>(logits, boxes, osz, out, cand,
                                                cnt8);
  } else {
    detr_post_mono<<<nbatch, THREADS, 0, stream>>>(logits, boxes, osz, out);
  }
}